// Round 2
// baseline (504.495 us; speedup 1.0000x reference)
//
#include <hip/hip_runtime.h>

// ---------------- constants ----------------
#define NTOP   4096
#define SORTN  8192
#define CONF_T 0.5f
#define IOU_T  0.6f

// ws layout (bytes)
#define HIST_OFF   0          // 2048 * u32 = 8 KB
#define CUT_OFF    8192       // int
#define CNT_OFF    8196       // u32
#define COMP_OFF   16384      // 8192 * u64 = 64 KB  (zeroed)
#define MEMSET_BYTES 81920    // covers hist+cut+cnt+comp
#define KEYS_OFF   131072     // 200000 * u64 = 1.6 MB
#define TB_OFF     2097152    // 4096 * float4 = 64 KB
#define TC_OFF     2162688    // 4096 * float  = 16 KB
#define VALID_OFF  2179072    // 64 * u64
#define KEEP_OFF   2179584    // 64 * u64
#define MASK_OFF   4194304    // 4096*64*u64 = 2 MB

typedef unsigned long long u64;
typedef unsigned int u32;

// K1: build keys + histogram of top-20 bits of score (valid only)
__global__ void k_keys(const float* __restrict__ confs, u64* __restrict__ keys,
                       u32* __restrict__ hist, int n) {
    int i = blockIdx.x * 256 + threadIdx.x;
    if (i >= n) return;
    float s = confs[i];
    if (s >= CONF_T) {
        u32 u = __float_as_uint(s);              // positive -> bits monotone
        keys[i] = ((u64)u << 32) | (u32)(~i);    // tie: lower index wins
        int bin = (int)(u >> 12) - 0x3F000;      // [0.5,1) -> [0,2047]
        bin = bin < 0 ? 0 : (bin > 2047 ? 2047 : bin);
        atomicAdd(&hist[bin], 1u);
    } else {
        keys[i] = 0ull;
    }
}

// K2: find cut bucket (largest b with suffix-count >= NTOP), single block
__global__ __launch_bounds__(256) void k_findcut(const u32* __restrict__ hist,
                                                 int* __restrict__ cut) {
    __shared__ u32 ch[256];
    int t = threadIdx.x;
    u32 h[8]; u32 s = 0;
#pragma unroll
    for (int k = 0; k < 8; ++k) { h[k] = hist[t * 8 + k]; s += h[k]; }
    ch[t] = s;
    __syncthreads();
    // inclusive suffix scan of chunk sums
    for (int off = 1; off < 256; off <<= 1) {
        u32 v = ch[t];
        u32 add = (t + off < 256) ? ch[t + off] : 0u;
        __syncthreads();
        ch[t] = v + add;
        __syncthreads();
    }
    u32 incl = ch[t];            // sum over bins >= t*8
    u32 above = incl - s;        // sum over bins >= (t+1)*8
    if (above < NTOP && incl >= NTOP) {
        u32 cum = above; int c = 0;
        for (int k = 7; k >= 0; --k) {
            cum += h[k];
            if (cum >= NTOP) { c = t * 8 + k; break; }
        }
        *cut = c;
    }
    if (t == 0 && ch[0] < NTOP) *cut = 0;   // fewer than NTOP valid: take all
}

// K3: compact candidates with bucket >= cut
__global__ void k_compact(const u64* __restrict__ keys, const int* __restrict__ cut,
                          u64* __restrict__ comp, u32* __restrict__ counter, int n) {
    int i = blockIdx.x * 256 + threadIdx.x;
    if (i >= n) return;
    u64 key = keys[i];
    if (!key) return;
    int bin = (int)(u32)(key >> 44) - 0x3F000;
    bin = bin < 0 ? 0 : (bin > 2047 ? 2047 : bin);
    if (bin >= *cut) {
        u32 p = atomicAdd(counter, 1u);
        if (p < SORTN) comp[p] = key;
    }
}

// K4: bitonic sort SORTN u64 keys descending, single block, 64KB LDS
__global__ __launch_bounds__(1024) void k_sort(u64* __restrict__ comp) {
    __shared__ u64 sm[SORTN];
    int t = threadIdx.x;
    for (int i = t; i < SORTN; i += 1024) sm[i] = comp[i];
    __syncthreads();
    for (int k = 2; k <= SORTN; k <<= 1) {
        for (int j = k >> 1; j > 0; j >>= 1) {
            for (int i = t; i < SORTN; i += 1024) {
                int ixj = i ^ j;
                if (ixj > i) {
                    u64 a = sm[i], b = sm[ixj];
                    bool sw = ((i & k) == 0) ? (a < b) : (a > b);  // descending
                    if (sw) { sm[i] = b; sm[ixj] = a; }
                }
            }
            __syncthreads();
        }
    }
    for (int i = t; i < SORTN; i += 1024) comp[i] = sm[i];
}

// K5: gather top boxes/scores, build valid bitmask
__global__ void k_gather(const u64* __restrict__ skeys, const float4* __restrict__ boxes,
                         float4* __restrict__ tb, float* __restrict__ tc,
                         u64* __restrict__ validmask) {
    int k = blockIdx.x * 256 + threadIdx.x;   // 16 blocks -> 4096
    u64 key = skeys[k];
    float score = __uint_as_float((u32)(key >> 32));
    bool valid = (key != 0ull) && (score >= CONF_T);
    float4 b = make_float4(0.f, 0.f, 0.f, 0.f);
    if (valid) {
        u32 idx = ~(u32)(key & 0xFFFFFFFFull);
        b = boxes[idx];
    }
    tb[k] = b;
    tc[k] = score;
    u64 bal = __ballot(valid);
    if ((threadIdx.x & 63) == 0) validmask[k >> 6] = bal;
}

// K6: suppression bitmask matrix: mask[row][w] bit j = iou(row, w*64+j) > T
__global__ __launch_bounds__(256) void k_mask(const float4* __restrict__ tb,
                                              u64* __restrict__ mask) {
    __shared__ float4 cb[64];
    __shared__ float  ca[64];
    int w = blockIdx.x;           // word 0..63
    int t = threadIdx.x;
    if (t < 64) {
        float4 b = tb[w * 64 + t];
        cb[t] = b;
        ca[t] = fmaxf(b.z - b.x, 0.f) * fmaxf(b.w - b.y, 0.f);
    }
    __syncthreads();
    int row = blockIdx.y * 256 + t;
    float4 rb = tb[row];
    float ra = fmaxf(rb.z - rb.x, 0.f) * fmaxf(rb.w - rb.y, 0.f);
    u64 m = 0;
#pragma unroll 8
    for (int j = 0; j < 64; ++j) {
        float4 c = cb[j];
        float lx = fmaxf(rb.x, c.x), ly = fmaxf(rb.y, c.y);
        float rx = fminf(rb.z, c.z), ry = fminf(rb.w, c.w);
        float iw = fmaxf(rx - lx, 0.f), ih = fmaxf(ry - ly, 0.f);
        float inter = iw * ih;
        float iou = inter / (ra + ca[j] - inter + 1e-9f);
        if (iou > IOU_T) m |= (1ull << j);
    }
    mask[(size_t)row * 64 + w] = m;
}

// K7: serial greedy NMS scan — single wave, lane w owns suppression word w
__global__ __launch_bounds__(64) void k_nms(const u64* __restrict__ mask,
                                            const u64* __restrict__ validmask,
                                            u64* __restrict__ keep) {
    __shared__ u64 dw[NTOP];      // diagonal words: mask[i][i>>6]
    int lane = threadIdx.x;
    for (int i = lane; i < NTOP; i += 64) dw[i] = mask[(size_t)i * 64 + (i >> 6)];
    u64 mysup = ~validmask[lane];
    __syncthreads();

    u64 mykeep = 0;
    u64 pf[16];
#pragma unroll
    for (int d = 0; d < 16; ++d) pf[d] = mask[(size_t)d * 64 + lane];

    for (int w = 0; w < 64; ++w) {
        u64 cur = __shfl(mysup, w);      // word w, all prior suppressions
        u64 blockkeep = 0;
        for (int sub = 0; sub < 64; sub += 16) {
#pragma unroll
            for (int d = 0; d < 16; ++d) {
                int i = (w << 6) + sub + d;
                int nxt = (i + 16 < NTOP) ? (i + 16) : i;
                u64 rowv = pf[d];
                pf[d] = mask[(size_t)nxt * 64 + lane];   // prefetch (off-chain)
                u64 dwv = dw[i];
                int bit = sub + d;
                bool is_keep = ((cur >> bit) & 1ull) == 0ull;
                if (is_keep) {
                    cur |= dwv;
                    mysup |= rowv;
                    blockkeep |= (1ull << bit);
                }
            }
        }
        if (lane == w) mykeep = blockkeep;
    }
    keep[lane] = mykeep;
}

// K8: write output [4096,5], zero suppressed rows
__global__ void k_out(const float4* __restrict__ tb, const float* __restrict__ tc,
                      const u64* __restrict__ keep, float* __restrict__ out) {
    int k = blockIdx.x * 256 + threadIdx.x;
    bool kp = (keep[k >> 6] >> (k & 63)) & 1ull;
    float4 b = tb[k];
    float c = tc[k];
    float* o = out + (size_t)k * 5;
    o[0] = kp ? b.x : 0.f;
    o[1] = kp ? b.y : 0.f;
    o[2] = kp ? b.z : 0.f;
    o[3] = kp ? b.w : 0.f;
    o[4] = kp ? c : 0.f;
}

extern "C" void kernel_launch(void* const* d_in, const int* in_sizes, int n_in,
                              void* d_out, int out_size, void* d_ws, size_t ws_size,
                              hipStream_t stream) {
    const float4* boxes = (const float4*)d_in[0];   // [1,N,4] f32
    const float*  confs = (const float*)d_in[1];    // [1,N]   f32
    float* out = (float*)d_out;                     // [4096,5] f32
    char* ws = (char*)d_ws;
    int n = in_sizes[1];

    u32* hist    = (u32*)(ws + HIST_OFF);
    int* cut     = (int*)(ws + CUT_OFF);
    u32* counter = (u32*)(ws + CNT_OFF);
    u64* comp    = (u64*)(ws + COMP_OFF);
    u64* keys    = (u64*)(ws + KEYS_OFF);
    float4* tb   = (float4*)(ws + TB_OFF);
    float*  tc   = (float*)(ws + TC_OFF);
    u64* validm  = (u64*)(ws + VALID_OFF);
    u64* keep    = (u64*)(ws + KEEP_OFF);
    u64* mask    = (u64*)(ws + MASK_OFF);

    hipMemsetAsync(ws, 0, MEMSET_BYTES, stream);
    k_keys<<<(n + 255) / 256, 256, 0, stream>>>(confs, keys, hist, n);
    k_findcut<<<1, 256, 0, stream>>>(hist, cut);
    k_compact<<<(n + 255) / 256, 256, 0, stream>>>(keys, cut, comp, counter, n);
    k_sort<<<1, 1024, 0, stream>>>(comp);
    k_gather<<<16, 256, 0, stream>>>(comp, boxes, tb, tc, validm);
    k_mask<<<dim3(64, 16), 256, 0, stream>>>(tb, mask);
    k_nms<<<1, 64, 0, stream>>>(mask, validm, keep);
    k_out<<<16, 256, 0, stream>>>(tb, tc, keep, out);
}

// Round 6
// 439.670 us; speedup vs baseline: 1.1474x; 1.1474x over previous
//
#include <hip/hip_runtime.h>

// ---------------- constants ----------------
#define NTOP   4096
#define SORTN  8192
#define CONF_T 0.5f
#define IOU_T  0.6f

// ws layout (bytes)
#define HIST_OFF   0          // 2048 * u32 = 8 KB
#define CUT_OFF    8192       // int
#define CNT_OFF    8196       // u32
#define COMP_OFF   16384      // 8192 * u64 = 64 KB  (zeroed)
#define MEMSET_BYTES 81920    // covers hist+cut+cnt+comp
#define KEYS_OFF   131072     // 200000 * u64 = 1.6 MB
#define TB_OFF     2097152    // 4096 * float4 = 64 KB
#define TC_OFF     2162688    // 4096 * float  = 16 KB
#define VALID_OFF  2179072    // 64 * u64
#define KEEP_OFF   2179584    // 64 * u64
#define MASK_OFF   4194304    // 4096*64*u64 = 2 MB

typedef unsigned long long u64;
typedef unsigned int u32;

// K1: build keys + histogram of top-20 bits of score (valid only)
__global__ void k_keys(const float* __restrict__ confs, u64* __restrict__ keys,
                       u32* __restrict__ hist, int n) {
    int i = blockIdx.x * 256 + threadIdx.x;
    if (i >= n) return;
    float s = confs[i];
    if (s >= CONF_T) {
        u32 u = __float_as_uint(s);              // positive -> bits monotone
        keys[i] = ((u64)u << 32) | (u32)(~i);    // tie: lower index wins
        int bin = (int)(u >> 12) - 0x3F000;      // [0.5,1) -> [0,2047]
        bin = bin < 0 ? 0 : (bin > 2047 ? 2047 : bin);
        atomicAdd(&hist[bin], 1u);
    } else {
        keys[i] = 0ull;
    }
}

// K2: find cut bucket (largest b with suffix-count >= NTOP), single block
__global__ __launch_bounds__(256) void k_findcut(const u32* __restrict__ hist,
                                                 int* __restrict__ cut) {
    __shared__ u32 ch[256];
    int t = threadIdx.x;
    u32 h[8]; u32 s = 0;
#pragma unroll
    for (int k = 0; k < 8; ++k) { h[k] = hist[t * 8 + k]; s += h[k]; }
    ch[t] = s;
    __syncthreads();
    // inclusive suffix scan of chunk sums
    for (int off = 1; off < 256; off <<= 1) {
        u32 v = ch[t];
        u32 add = (t + off < 256) ? ch[t + off] : 0u;
        __syncthreads();
        ch[t] = v + add;
        __syncthreads();
    }
    u32 incl = ch[t];            // sum over bins >= t*8
    u32 above = incl - s;        // sum over bins >= (t+1)*8
    if (above < NTOP && incl >= NTOP) {
        u32 cum = above; int c = 0;
        for (int k = 7; k >= 0; --k) {
            cum += h[k];
            if (cum >= NTOP) { c = t * 8 + k; break; }
        }
        *cut = c;
    }
    if (t == 0 && ch[0] < NTOP) *cut = 0;   // fewer than NTOP valid: take all
}

// K3: compact candidates with bucket >= cut
__global__ void k_compact(const u64* __restrict__ keys, const int* __restrict__ cut,
                          u64* __restrict__ comp, u32* __restrict__ counter, int n) {
    int i = blockIdx.x * 256 + threadIdx.x;
    if (i >= n) return;
    u64 key = keys[i];
    if (!key) return;
    int bin = (int)(u32)(key >> 44) - 0x3F000;
    bin = bin < 0 ? 0 : (bin > 2047 ? 2047 : bin);
    if (bin >= *cut) {
        u32 p = atomicAdd(counter, 1u);
        if (p < SORTN) comp[p] = key;
    }
}

// K4: bitonic sort SORTN u64 keys descending, single block, 64KB LDS.
// Epilogue (fused, was k_gather): gather top boxes/scores, build valid bitmask.
__global__ __launch_bounds__(1024) void k_sort(const u64* __restrict__ comp,
                                               const float4* __restrict__ boxes,
                                               float4* __restrict__ tb,
                                               float* __restrict__ tc,
                                               u64* __restrict__ validmask) {
    __shared__ u64 sm[SORTN];
    int t = threadIdx.x;
    for (int i = t; i < SORTN; i += 1024) sm[i] = comp[i];
    __syncthreads();
    for (int k = 2; k <= SORTN; k <<= 1) {
        for (int j = k >> 1; j > 0; j >>= 1) {
            for (int i = t; i < SORTN; i += 1024) {
                int ixj = i ^ j;
                if (ixj > i) {
                    u64 a = sm[i], b = sm[ixj];
                    bool sw = ((i & k) == 0) ? (a < b) : (a > b);  // descending
                    if (sw) { sm[i] = b; sm[ixj] = a; }
                }
            }
            __syncthreads();
        }
    }
    // fused gather: first NTOP sorted keys -> boxes/scores/valid bitmask
    for (int base = 0; base < NTOP; base += 1024) {
        int k = base + t;
        u64 key = sm[k];
        float score = __uint_as_float((u32)(key >> 32));
        bool valid = (key != 0ull) && (score >= CONF_T);
        float4 b = make_float4(0.f, 0.f, 0.f, 0.f);
        if (valid) {
            u32 idx = ~(u32)(key & 0xFFFFFFFFull);
            b = boxes[idx];
        }
        tb[k] = b;
        tc[k] = score;
        u64 bal = __ballot(valid);
        if ((t & 63) == 0) validmask[k >> 6] = bal;
    }
}

// K6: suppression bitmask matrix: mask[row][w] bit j = iou(row, w*64+j) > T
__global__ __launch_bounds__(256) void k_mask(const float4* __restrict__ tb,
                                              u64* __restrict__ mask) {
    __shared__ float4 cb[64];
    __shared__ float  ca[64];
    int w = blockIdx.x;           // word 0..63
    int t = threadIdx.x;
    if (t < 64) {
        float4 b = tb[w * 64 + t];
        cb[t] = b;
        ca[t] = fmaxf(b.z - b.x, 0.f) * fmaxf(b.w - b.y, 0.f);
    }
    __syncthreads();
    int row = blockIdx.y * 256 + t;
    float4 rb = tb[row];
    float ra = fmaxf(rb.z - rb.x, 0.f) * fmaxf(rb.w - rb.y, 0.f);
    u64 m = 0;
#pragma unroll 8
    for (int j = 0; j < 64; ++j) {
        float4 c = cb[j];
        float lx = fmaxf(rb.x, c.x), ly = fmaxf(rb.y, c.y);
        float rx = fminf(rb.z, c.z), ry = fminf(rb.w, c.w);
        float iw = fmaxf(rx - lx, 0.f), ih = fmaxf(ry - ly, 0.f);
        float inter = iw * ih;
        float iou = inter / (ra + ca[j] - inter + 1e-9f);
        if (iou > IOU_T) m |= (1ull << j);
    }
    mask[(size_t)row * 64 + w] = m;
}

// K7: serial greedy NMS scan — single wave, lane w owns suppression word w.
// Serial chain kept fully SCALAR (cur/blockkeep uniform via readlane);
// the diagonal word is lane w of the prefetched row (no LDS on the chain).
__global__ __launch_bounds__(64) void k_nms(const u64* __restrict__ mask,
                                            const u64* __restrict__ validmask,
                                            u64* __restrict__ keep) {
    int lane = threadIdx.x;
    u64 mysup = ~validmask[lane];
    u64 mykeep = 0;

    u64 pf[32];                  // 32-deep global prefetch rotation (static idx)
#pragma unroll
    for (int d = 0; d < 32; ++d) pf[d] = mask[(size_t)d * 64 + lane];

    for (int w = 0; w < 64; ++w) {
        // broadcast word w of the suppression state to scalar regs
        u32 clo = (u32)__builtin_amdgcn_readlane((int)(u32)mysup, w);
        u32 chi = (u32)__builtin_amdgcn_readlane((int)(u32)(mysup >> 32), w);
        u64 cur = ((u64)chi << 32) | clo;
        u64 blockkeep = 0;
#pragma unroll
        for (int sub = 0; sub < 64; sub += 32) {
#pragma unroll
            for (int d = 0; d < 32; ++d) {
                int i = (w << 6) + sub + d;
                int nxt = i + 32; if (nxt >= NTOP) nxt = i;
                u64 rowv = pf[d];                         // mask[i][lane]
                pf[d] = mask[(size_t)nxt * 64 + lane];    // prefetch (off-chain)
                // diagonal word mask[i][w] = lane w of rowv (scalar, off-chain)
                u32 dlo = (u32)__builtin_amdgcn_readlane((int)(u32)rowv, w);
                u32 dhi = (u32)__builtin_amdgcn_readlane((int)(u32)(rowv >> 32), w);
                u64 dwv = ((u64)dhi << 32) | dlo;
                const int bit = sub + d;                  // compile-time const
                bool is_keep = ((cur >> bit) & 1ull) == 0ull;
                u64 m = is_keep ? ~0ull : 0ull;           // uniform -> s_cselect
                cur |= dwv & m;                           // scalar chain
                mysup |= rowv & m;                        // vector accumulate
                blockkeep |= is_keep ? (1ull << bit) : 0ull;
            }
        }
        if (lane == w) mykeep = blockkeep;
    }
    keep[lane] = mykeep;
}

// K8: write output [4096,5], zero suppressed rows
__global__ void k_out(const float4* __restrict__ tb, const float* __restrict__ tc,
                      const u64* __restrict__ keep, float* __restrict__ out) {
    int k = blockIdx.x * 256 + threadIdx.x;
    bool kp = (keep[k >> 6] >> (k & 63)) & 1ull;
    float4 b = tb[k];
    float c = tc[k];
    float* o = out + (size_t)k * 5;
    o[0] = kp ? b.x : 0.f;
    o[1] = kp ? b.y : 0.f;
    o[2] = kp ? b.z : 0.f;
    o[3] = kp ? b.w : 0.f;
    o[4] = kp ? c : 0.f;
}

extern "C" void kernel_launch(void* const* d_in, const int* in_sizes, int n_in,
                              void* d_out, int out_size, void* d_ws, size_t ws_size,
                              hipStream_t stream) {
    const float4* boxes = (const float4*)d_in[0];   // [1,N,4] f32
    const float*  confs = (const float*)d_in[1];    // [1,N]   f32
    float* out = (float*)d_out;                     // [4096,5] f32
    char* ws = (char*)d_ws;
    int n = in_sizes[1];

    u32* hist    = (u32*)(ws + HIST_OFF);
    int* cut     = (int*)(ws + CUT_OFF);
    u32* counter = (u32*)(ws + CNT_OFF);
    u64* comp    = (u64*)(ws + COMP_OFF);
    u64* keys    = (u64*)(ws + KEYS_OFF);
    float4* tb   = (float4*)(ws + TB_OFF);
    float*  tc   = (float*)(ws + TC_OFF);
    u64* validm  = (u64*)(ws + VALID_OFF);
    u64* keep    = (u64*)(ws + KEEP_OFF);
    u64* mask    = (u64*)(ws + MASK_OFF);

    hipMemsetAsync(ws, 0, MEMSET_BYTES, stream);
    k_keys<<<(n + 255) / 256, 256, 0, stream>>>(confs, keys, hist, n);
    k_findcut<<<1, 256, 0, stream>>>(hist, cut);
    k_compact<<<(n + 255) / 256, 256, 0, stream>>>(keys, cut, comp, counter, n);
    k_sort<<<1, 1024, 0, stream>>>(comp, boxes, tb, tc, validm);
    k_mask<<<dim3(64, 16), 256, 0, stream>>>(tb, mask);
    k_nms<<<1, 64, 0, stream>>>(mask, validm, keep);
    k_out<<<16, 256, 0, stream>>>(tb, tc, keep, out);
}

// Round 7
// 431.275 us; speedup vs baseline: 1.1698x; 1.0195x over previous
//
#include <hip/hip_runtime.h>

// ---------------- constants ----------------
#define NTOP   4096
#define SORTN  8192
#define CONF_T 0.5f
#define IOU_T  0.6f

// ws layout (bytes)
#define HIST_OFF   0          // 2048 * u32 = 8 KB
#define CUT_OFF    8192       // int
#define CNT_OFF    8196       // u32
#define COMP_OFF   16384      // 8192 * u64 = 64 KB  (zeroed)
#define MEMSET_BYTES 81920    // covers hist+cut+cnt+comp
#define KEYS_OFF   131072     // 200000 * u64 = 1.6 MB
#define TB_OFF     2097152    // 4096 * float4 = 64 KB
#define TC_OFF     2162688    // 4096 * float  = 16 KB
#define VALID_OFF  2179072    // 64 * u64
#define KEEP_OFF   2179584    // 64 * u64
#define MASK_OFF   4194304    // 4096*64*u64 = 2 MB

typedef unsigned long long u64;
typedef unsigned int u32;

// K1: build keys + histogram of top-20 bits of score (valid only)
__global__ void k_keys(const float* __restrict__ confs, u64* __restrict__ keys,
                       u32* __restrict__ hist, int n) {
    int i = blockIdx.x * 256 + threadIdx.x;
    if (i >= n) return;
    float s = confs[i];
    if (s >= CONF_T) {
        u32 u = __float_as_uint(s);              // positive -> bits monotone
        keys[i] = ((u64)u << 32) | (u32)(~i);    // tie: lower index wins
        int bin = (int)(u >> 12) - 0x3F000;      // [0.5,1) -> [0,2047]
        bin = bin < 0 ? 0 : (bin > 2047 ? 2047 : bin);
        atomicAdd(&hist[bin], 1u);
    } else {
        keys[i] = 0ull;
    }
}

// K2: find cut bucket (largest b with suffix-count >= NTOP), single block
__global__ __launch_bounds__(256) void k_findcut(const u32* __restrict__ hist,
                                                 int* __restrict__ cut) {
    __shared__ u32 ch[256];
    int t = threadIdx.x;
    u32 h[8]; u32 s = 0;
#pragma unroll
    for (int k = 0; k < 8; ++k) { h[k] = hist[t * 8 + k]; s += h[k]; }
    ch[t] = s;
    __syncthreads();
    // inclusive suffix scan of chunk sums
    for (int off = 1; off < 256; off <<= 1) {
        u32 v = ch[t];
        u32 add = (t + off < 256) ? ch[t + off] : 0u;
        __syncthreads();
        ch[t] = v + add;
        __syncthreads();
    }
    u32 incl = ch[t];            // sum over bins >= t*8
    u32 above = incl - s;        // sum over bins >= (t+1)*8
    if (above < NTOP && incl >= NTOP) {
        u32 cum = above; int c = 0;
        for (int k = 7; k >= 0; --k) {
            cum += h[k];
            if (cum >= NTOP) { c = t * 8 + k; break; }
        }
        *cut = c;
    }
    if (t == 0 && ch[0] < NTOP) *cut = 0;   // fewer than NTOP valid: take all
}

// K3: compact candidates with bucket >= cut
__global__ void k_compact(const u64* __restrict__ keys, const int* __restrict__ cut,
                          u64* __restrict__ comp, u32* __restrict__ counter, int n) {
    int i = blockIdx.x * 256 + threadIdx.x;
    if (i >= n) return;
    u64 key = keys[i];
    if (!key) return;
    int bin = (int)(u32)(key >> 44) - 0x3F000;
    bin = bin < 0 ? 0 : (bin > 2047 ? 2047 : bin);
    if (bin >= *cut) {
        u32 p = atomicAdd(counter, 1u);
        if (p < SORTN) comp[p] = key;
    }
}

// K4: bitonic sort SORTN u64 keys descending, single block, 64KB LDS.
// Epilogue (fused, was k_gather): gather top boxes/scores, build valid bitmask.
__global__ __launch_bounds__(1024) void k_sort(const u64* __restrict__ comp,
                                               const float4* __restrict__ boxes,
                                               float4* __restrict__ tb,
                                               float* __restrict__ tc,
                                               u64* __restrict__ validmask) {
    __shared__ u64 sm[SORTN];
    int t = threadIdx.x;
    for (int i = t; i < SORTN; i += 1024) sm[i] = comp[i];
    __syncthreads();
    for (int k = 2; k <= SORTN; k <<= 1) {
        for (int j = k >> 1; j > 0; j >>= 1) {
            for (int i = t; i < SORTN; i += 1024) {
                int ixj = i ^ j;
                if (ixj > i) {
                    u64 a = sm[i], b = sm[ixj];
                    bool sw = ((i & k) == 0) ? (a < b) : (a > b);  // descending
                    if (sw) { sm[i] = b; sm[ixj] = a; }
                }
            }
            __syncthreads();
        }
    }
    // fused gather: first NTOP sorted keys -> boxes/scores/valid bitmask
    for (int base = 0; base < NTOP; base += 1024) {
        int k = base + t;
        u64 key = sm[k];
        float score = __uint_as_float((u32)(key >> 32));
        bool valid = (key != 0ull) && (score >= CONF_T);
        float4 b = make_float4(0.f, 0.f, 0.f, 0.f);
        if (valid) {
            u32 idx = ~(u32)(key & 0xFFFFFFFFull);
            b = boxes[idx];
        }
        tb[k] = b;
        tc[k] = score;
        u64 bal = __ballot(valid);
        if ((t & 63) == 0) validmask[k >> 6] = bal;
    }
}

// K6: suppression bitmask matrix: mask[row][w] bit j = iou(row, w*64+j) > T
__global__ __launch_bounds__(256) void k_mask(const float4* __restrict__ tb,
                                              u64* __restrict__ mask) {
    __shared__ float4 cb[64];
    __shared__ float  ca[64];
    int w = blockIdx.x;           // word 0..63
    int t = threadIdx.x;
    if (t < 64) {
        float4 b = tb[w * 64 + t];
        cb[t] = b;
        ca[t] = fmaxf(b.z - b.x, 0.f) * fmaxf(b.w - b.y, 0.f);
    }
    __syncthreads();
    int row = blockIdx.y * 256 + t;
    float4 rb = tb[row];
    float ra = fmaxf(rb.z - rb.x, 0.f) * fmaxf(rb.w - rb.y, 0.f);
    u64 m = 0;
#pragma unroll 8
    for (int j = 0; j < 64; ++j) {
        float4 c = cb[j];
        float lx = fmaxf(rb.x, c.x), ly = fmaxf(rb.y, c.y);
        float rx = fminf(rb.z, c.z), ry = fminf(rb.w, c.w);
        float iw = fmaxf(rx - lx, 0.f), ih = fmaxf(ry - ly, 0.f);
        float inter = iw * ih;
        float iou = inter / (ra + ca[j] - inter + 1e-9f);
        if (iou > IOU_T) m |= (1ull << j);
    }
    mask[(size_t)row * 64 + w] = m;
}

// K7: serial greedy NMS scan — single wave, lane w owns suppression word w.
// Serial chain fully SCALAR; diagonal word is lane w of the prefetched row.
// __launch_bounds__(64, 1): this is ONE wave on the whole GPU — request the
// full VGPR budget so pf[32] (64 VGPRs) stays in registers (r6: default
// 8-waves/EU budget of 64 VGPRs spilled it to scratch -> 113 cy/iter).
__global__ __launch_bounds__(64, 1) void k_nms(const u64* __restrict__ mask,
                                               const u64* __restrict__ validmask,
                                               u64* __restrict__ keep) {
    int lane = threadIdx.x;
    u64 mysup = ~validmask[lane];
    u64 mykeep = 0;

    u64 pf[32];                  // 32-deep global prefetch rotation (static idx)
#pragma unroll
    for (int d = 0; d < 32; ++d) pf[d] = mask[(size_t)d * 64 + lane];

    for (int w = 0; w < 64; ++w) {
        // broadcast word w of the suppression state to scalar regs
        u32 clo = (u32)__builtin_amdgcn_readlane((int)(u32)mysup, w);
        u32 chi = (u32)__builtin_amdgcn_readlane((int)(u32)(mysup >> 32), w);
        u64 cur = ((u64)chi << 32) | clo;
        u64 blockkeep = 0;
#pragma unroll
        for (int sub = 0; sub < 64; sub += 32) {
#pragma unroll
            for (int d = 0; d < 32; ++d) {
                int i = (w << 6) + sub + d;
                int nxt = i + 32; if (nxt >= NTOP) nxt = i;
                u64 rowv = pf[d];                         // mask[i][lane]
                pf[d] = mask[(size_t)nxt * 64 + lane];    // prefetch (off-chain)
                // diagonal word mask[i][w] = lane w of rowv (scalar, off-chain)
                u32 dlo = (u32)__builtin_amdgcn_readlane((int)(u32)rowv, w);
                u32 dhi = (u32)__builtin_amdgcn_readlane((int)(u32)(rowv >> 32), w);
                u64 dwv = ((u64)dhi << 32) | dlo;
                const int bit = sub + d;                  // compile-time const
                bool is_keep = ((cur >> bit) & 1ull) == 0ull;
                u64 m = is_keep ? ~0ull : 0ull;           // uniform -> s_cselect
                cur |= dwv & m;                           // scalar chain
                mysup |= rowv & m;                        // vector accumulate
                blockkeep |= is_keep ? (1ull << bit) : 0ull;
            }
        }
        if (lane == w) mykeep = blockkeep;
    }
    keep[lane] = mykeep;
}

// K8: write output [4096,5], zero suppressed rows
__global__ void k_out(const float4* __restrict__ tb, const float* __restrict__ tc,
                      const u64* __restrict__ keep, float* __restrict__ out) {
    int k = blockIdx.x * 256 + threadIdx.x;
    bool kp = (keep[k >> 6] >> (k & 63)) & 1ull;
    float4 b = tb[k];
    float c = tc[k];
    float* o = out + (size_t)k * 5;
    o[0] = kp ? b.x : 0.f;
    o[1] = kp ? b.y : 0.f;
    o[2] = kp ? b.z : 0.f;
    o[3] = kp ? b.w : 0.f;
    o[4] = kp ? c : 0.f;
}

extern "C" void kernel_launch(void* const* d_in, const int* in_sizes, int n_in,
                              void* d_out, int out_size, void* d_ws, size_t ws_size,
                              hipStream_t stream) {
    const float4* boxes = (const float4*)d_in[0];   // [1,N,4] f32
    const float*  confs = (const float*)d_in[1];    // [1,N]   f32
    float* out = (float*)d_out;                     // [4096,5] f32
    char* ws = (char*)d_ws;
    int n = in_sizes[1];

    u32* hist    = (u32*)(ws + HIST_OFF);
    int* cut     = (int*)(ws + CUT_OFF);
    u32* counter = (u32*)(ws + CNT_OFF);
    u64* comp    = (u64*)(ws + COMP_OFF);
    u64* keys    = (u64*)(ws + KEYS_OFF);
    float4* tb   = (float4*)(ws + TB_OFF);
    float*  tc   = (float*)(ws + TC_OFF);
    u64* validm  = (u64*)(ws + VALID_OFF);
    u64* keep    = (u64*)(ws + KEEP_OFF);
    u64* mask    = (u64*)(ws + MASK_OFF);

    hipMemsetAsync(ws, 0, MEMSET_BYTES, stream);
    k_keys<<<(n + 255) / 256, 256, 0, stream>>>(confs, keys, hist, n);
    k_findcut<<<1, 256, 0, stream>>>(hist, cut);
    k_compact<<<(n + 255) / 256, 256, 0, stream>>>(keys, cut, comp, counter, n);
    k_sort<<<1, 1024, 0, stream>>>(comp, boxes, tb, tc, validm);
    k_mask<<<dim3(64, 16), 256, 0, stream>>>(tb, mask);
    k_nms<<<1, 64, 0, stream>>>(mask, validm, keep);
    k_out<<<16, 256, 0, stream>>>(tb, tc, keep, out);
}